// Round 2
// baseline (4810.770 us; speedup 1.0000x reference)
//
#include <hip/hip_runtime.h>
#include <hip/hip_bf16.h>
#include <stdint.h>

// WaveNet forward, MI355X/gfx950.
// B=8, T=16384, IN=256, RES=128, SKIP=256, L=30, dilations 2^(i%10).
// bf16 MFMA (16x16x32) everywhere, fp32 residual chain + fp32 skip accumulator.
// h ping-pong lives inside d_out (dead before final kernel overwrites it).
// Skip GEMM fused into the layer kernel (RMW fp32 skip buffer in ws).

typedef __attribute__((ext_vector_type(8))) short s16x8;
typedef __attribute__((ext_vector_type(4))) short s16x4;
typedef __attribute__((ext_vector_type(4))) float f32x4;

__device__ __forceinline__ short f2bf(float f) {
  union { float f; uint32_t u; } v; v.f = f;
  uint32_t u = v.u;
  uint32_t r = (u + 0x7FFFu + ((u >> 16) & 1u)) >> 16;   // RNE
  return (short)r;
}

// XOR-swizzled byte offsets for [rows][128ch] / [rows][256ch] bf16 LDS tiles.
__device__ __forceinline__ int swz128(int row, int c) {
  return row * 256 + ((((c >> 3) ^ (row & 7))) << 4) + ((c & 7) << 1);
}
__device__ __forceinline__ int swz256(int row, int c) {
  return row * 512 + ((((c >> 3) ^ (row & 7))) << 4) + ((c & 7) << 1);
}

// A/B fragment element index for mfma_f32_16x16x32_bf16:
// lane = (m&15) | (((k>>3)&3)<<4), elem j = k&7, frag (mb,kb) contiguous.
// (Any hw k-permutation cancels: same map used for A pack and B read.)
__device__ __forceinline__ size_t frag_idx(int m, int k, int K) {
  int lane = (m & 15) | (((k >> 3) & 3) << 4);
  return ((size_t)((m >> 4) * (K >> 5) + (k >> 5)) * 64 + lane) * 8 + (k & 7);
}

__device__ __forceinline__ f32x4 mfma16(s16x8 a, s16x8 b, f32x4 c) {
  return __builtin_amdgcn_mfma_f32_16x16x32_bf16(a, b, c, 0, 0, 0);
}

__device__ __forceinline__ float tanh_f(float x) {
  return 1.f - 2.f / (__expf(2.f * x) + 1.f);
}
__device__ __forceinline__ float sigm_f(float x) {
  return 1.f / (1.f + __expf(-x));
}

// ---------------- packing kernels (run every call; ws is re-poisoned) -------

// x [8][256][16384] fp32 -> B-fragment-packed bf16 [b][nb(1024)][kb(8)][lane][8]
__global__ __launch_bounds__(256) void pack_x(const float* __restrict__ x,
                                              short* __restrict__ xB) {
  size_t i = (size_t)blockIdx.x * 256 + threadIdx.x;   // 4,194,304 total
  int l = (int)(i & 63);
  size_t r = i >> 6;
  int kb = (int)(r & 7); r >>= 3;
  int nb = (int)(r & 1023);
  int b = (int)(r >> 10);
  int t = (nb << 4) + (l & 15);
  int c0 = (kb << 5) + ((l >> 4) << 3);
  const float* xs = x + (size_t)(b * 256 + c0) * 16384 + t;
  s16x8 v;
#pragma unroll
  for (int j = 0; j < 8; ++j) v[j] = f2bf(xs[(size_t)j * 16384]);
  *(s16x8*)(xB + (i << 3)) = v;
}

// Wf,Wg [30][128][128][2] -> stacked A [30][M=256][K=256], k = tap*128 + ic
__global__ __launch_bounds__(256) void pack_fg(const float* __restrict__ Wf,
                                               const float* __restrict__ Wg,
                                               short* __restrict__ A) {
  int i = blockIdx.x * 256 + threadIdx.x;
  if (i >= 30 * 256 * 256) return;
  int l = i >> 16, rem = i & 65535;
  int m = rem >> 8, k = rem & 255;
  int ic = k & 127, tap = k >> 7;
  float v = (m < 128)
      ? Wf[((size_t)(l * 128 + m) * 128 + ic) * 2 + tap]
      : Wg[((size_t)(l * 128 + (m - 128)) * 128 + ic) * 2 + tap];
  A[(size_t)l * 65536 + frag_idx(m, k, 256)] = f2bf(v);
}

// generic [nmat][M][K] fp32 (K-contiguous) -> packed A bf16
__global__ __launch_bounds__(256) void pack_mats(const float* __restrict__ W,
                                                 short* __restrict__ A,
                                                 int M, int K, int total) {
  int i = blockIdx.x * 256 + threadIdx.x;
  if (i >= total) return;
  int mk = M * K;
  int l = i / mk, rem = i - l * mk;
  int m = rem / K, k = rem - m * K;
  A[(size_t)l * mk + frag_idx(m, k, K)] = f2bf(W[i]);
}

__global__ void sum_bs_k(const float* __restrict__ bs, float* __restrict__ sbs) {
  int c = threadIdx.x;
  float s = 0.f;
  for (int l = 0; l < 30; ++l) s += bs[l * 256 + c];
  sbs[c] = s;
}

__global__ __launch_bounds__(256) void sentinel_fill(float* __restrict__ out, int n) {
  int i = blockIdx.x * 256 + threadIdx.x;
  if (i < n) out[i] = -54321.0f;
}

// ---------------- initial 1x1 conv: h0 = W_init x + b_init ------------------

__global__ __launch_bounds__(256) void init_kernel(const short* __restrict__ xB,
                                                   const short* __restrict__ Ai,
                                                   const float* __restrict__ b_init,
                                                   float* __restrict__ h0) {
  const int tid = threadIdx.x, lane = tid & 63, w = tid >> 6;
  const int b = blockIdx.x >> 8, t0 = (blockIdx.x & 255) << 6;
  const short* __restrict__ xb = xB + (size_t)((b << 10) + (t0 >> 4)) * 4096;
  f32x4 acc[2][4] = {};
#pragma unroll
  for (int kb = 0; kb < 8; ++kb) {
    s16x8 bx[4];
#pragma unroll
    for (int nb = 0; nb < 4; ++nb)
      bx[nb] = *(const s16x8*)(xb + (((nb * 8 + kb) * 64 + lane) << 3));
#pragma unroll
    for (int mi = 0; mi < 2; ++mi) {
      s16x8 a = *(const s16x8*)(Ai + ((((2 * w + mi) * 8 + kb) * 64 + lane) << 3));
#pragma unroll
      for (int nb = 0; nb < 4; ++nb) acc[mi][nb] = mfma16(a, bx[nb], acc[mi][nb]);
    }
  }
  const int qrow = (lane >> 4) << 2;
  float* __restrict__ ho = h0 + (size_t)b * 16384 * 128;
#pragma unroll
  for (int mi = 0; mi < 2; ++mi) {
    const int c0 = 32 * w + 16 * mi + qrow;
#pragma unroll
    for (int nb = 0; nb < 4; ++nb) {
      const int tg = t0 + nb * 16 + (lane & 15);
      f32x4 ov;
#pragma unroll
      for (int r = 0; r < 4; ++r) ov[r] = acc[mi][nb][r] + b_init[c0 + r];
      *(f32x4*)(ho + (size_t)tg * 128 + c0) = ov;
    }
  }
}

// ---------------- residual layer (skip fused) -------------------------------
// f = tanh(Wf0 h[t-d] + Wf1 h[t] + bf), g = sigm(...), z = f*g
// h_out = h_in + Wr z + br ; skip (+)= Ws z   (fp32 RMW, layer0 plain write)

__global__ __launch_bounds__(256) void layer_kernel(
    const float* __restrict__ h_in, float* __restrict__ h_out,
    const short* __restrict__ Afg, const short* __restrict__ Ar,
    const short* __restrict__ As, float* __restrict__ skip,
    const float* __restrict__ bfv, const float* __restrict__ bgv,
    const float* __restrict__ brv, int d, int first) {
  __shared__ short hl[128 * 128];   // rows 0..63: h[t0-d+r], 64..127: h[t0+r]
  __shared__ short zl[64 * 128];
  const int tid = threadIdx.x, lane = tid & 63, w = tid >> 6;
  const int b = blockIdx.x >> 8, t0 = (blockIdx.x & 255) << 6;
  const float* __restrict__ hb = h_in + (size_t)b * 16384 * 128;

#pragma unroll
  for (int it = 0; it < 8; ++it) {
    int lin = it * 256 + tid;
    int r = lin >> 4, s = lin & 15;
    int tg = (r < 64) ? (t0 - d + r) : (t0 + r - 64);
    s16x8 v;
    if (tg < 0) {
      v = (s16x8)0;
    } else {
      const float* src = hb + (size_t)tg * 128 + s * 8;
      f32x4 a0 = *(const f32x4*)src;
      f32x4 a1 = *(const f32x4*)(src + 4);
      v[0] = f2bf(a0[0]); v[1] = f2bf(a0[1]); v[2] = f2bf(a0[2]); v[3] = f2bf(a0[3]);
      v[4] = f2bf(a1[0]); v[5] = f2bf(a1[1]); v[6] = f2bf(a1[2]); v[7] = f2bf(a1[3]);
    }
    *(s16x8*)((char*)hl + swz128(r, s * 8)) = v;
  }
  __syncthreads();

  // FG GEMM: M=256 stacked [f;g], K=256 (kb<4: prev-tap rows, kb>=4: cur rows)
  f32x4 acc[4][4] = {};
#pragma unroll
  for (int kb = 0; kb < 8; ++kb) {
    const int rbase = (kb >= 4) ? 64 : 0;
    const int icb = (kb & 3) * 32 + ((lane >> 4) << 3);
    s16x8 bfr[4];
#pragma unroll
    for (int nb = 0; nb < 4; ++nb)
      bfr[nb] = *(const s16x8*)((const char*)hl + swz128(rbase + nb * 16 + (lane & 15), icb));
    s16x8 afr[4];
#pragma unroll
    for (int mi = 0; mi < 4; ++mi) {
      int mb = (mi < 2) ? (2 * w + mi) : (6 + 2 * w + mi);   // f: 2w,2w+1 ; g: 8+2w,8+2w+1
      afr[mi] = *(const s16x8*)(Afg + (((mb * 8 + kb) * 64 + lane) << 3));
    }
#pragma unroll
    for (int mi = 0; mi < 4; ++mi)
#pragma unroll
      for (int nb = 0; nb < 4; ++nb)
        acc[mi][nb] = mfma16(afr[mi], bfr[nb], acc[mi][nb]);
  }

  // gated activation; z -> LDS
  const int qrow = (lane >> 4) << 2;
#pragma unroll
  for (int mi = 0; mi < 2; ++mi) {
    const int c0 = 32 * w + 16 * mi + qrow;
#pragma unroll
    for (int nb = 0; nb < 4; ++nb) {
      const int tl = nb * 16 + (lane & 15);
      s16x4 zp;
#pragma unroll
      for (int r = 0; r < 4; ++r) {
        float fv = acc[mi][nb][r] + bfv[c0 + r];
        float gv = acc[mi + 2][nb][r] + bgv[c0 + r];
        zp[r] = f2bf(tanh_f(fv) * sigm_f(gv));
      }
      *(s16x4*)((char*)zl + swz128(tl, c0)) = zp;
    }
  }
  __syncthreads();

  // merged R (M=128) + S (M=256) GEMM over shared z B-fragments, K=128
  f32x4 racc[2][4] = {};
  f32x4 sacc[4][4] = {};
#pragma unroll
  for (int kb = 0; kb < 4; ++kb) {
    const int icb = kb * 32 + ((lane >> 4) << 3);
    s16x8 bz[4];
#pragma unroll
    for (int nb = 0; nb < 4; ++nb)
      bz[nb] = *(const s16x8*)((const char*)zl + swz128(nb * 16 + (lane & 15), icb));
#pragma unroll
    for (int mi = 0; mi < 2; ++mi) {
      s16x8 ar = *(const s16x8*)(Ar + ((((2 * w + mi) * 4 + kb) * 64 + lane) << 3));
#pragma unroll
      for (int nb = 0; nb < 4; ++nb)
        racc[mi][nb] = mfma16(ar, bz[nb], racc[mi][nb]);
    }
#pragma unroll
    for (int mi = 0; mi < 4; ++mi) {
      s16x8 as_ = *(const s16x8*)(As + ((((4 * w + mi) * 4 + kb) * 64 + lane) << 3));
#pragma unroll
      for (int nb = 0; nb < 4; ++nb)
        sacc[mi][nb] = mfma16(as_, bz[nb], sacc[mi][nb]);
    }
  }

  // h_out = h_in + r + br
  float* __restrict__ ho = h_out + (size_t)b * 16384 * 128;
#pragma unroll
  for (int mi = 0; mi < 2; ++mi) {
    const int c0 = 32 * w + 16 * mi + qrow;
#pragma unroll
    for (int nb = 0; nb < 4; ++nb) {
      const int tg = t0 + nb * 16 + (lane & 15);
      f32x4 hv = *(const f32x4*)(hb + (size_t)tg * 128 + c0);
      f32x4 ov;
#pragma unroll
      for (int r = 0; r < 4; ++r) ov[r] = hv[r] + racc[mi][nb][r] + brv[c0 + r];
      *(f32x4*)(ho + (size_t)tg * 128 + c0) = ov;
    }
  }

  // skip accumulate (fp32). layer0: plain write.
  float* __restrict__ sk = skip + (size_t)b * 16384 * 256;
#pragma unroll
  for (int mi = 0; mi < 4; ++mi) {
    const int c0 = (4 * w + mi) * 16 + qrow;
#pragma unroll
    for (int nb = 0; nb < 4; ++nb) {
      const int tg = t0 + nb * 16 + (lane & 15);
      float* sp = sk + (size_t)tg * 256 + c0;
      f32x4 ov;
      if (first) {
#pragma unroll
        for (int r = 0; r < 4; ++r) ov[r] = sacc[mi][nb][r];
      } else {
        f32x4 sv = *(const f32x4*)sp;
#pragma unroll
        for (int r = 0; r < 4; ++r) ov[r] = sv[r] + sacc[mi][nb][r];
      }
      *(f32x4*)sp = ov;
    }
  }
}

// ---------------- final: relu(skip+sbs) -> W1 -> relu -> W2 -> out ----------

__global__ __launch_bounds__(256) void final_kernel(
    const float* __restrict__ skip, const short* __restrict__ A1,
    const short* __restrict__ A2, const float* __restrict__ sbs,
    const float* __restrict__ b1, const float* __restrict__ b2,
    float* __restrict__ out) {
  __shared__ short sb[64 * 256];
  const int tid = threadIdx.x, lane = tid & 63, w = tid >> 6;
  const int b = blockIdx.x >> 8, t0 = (blockIdx.x & 255) << 6;
  const int qrow = (lane >> 4) << 2;

  // stage relu(skip + sbs) -> sb (bf16, swizzled)
  const float* __restrict__ sk = skip + ((size_t)b * 16384 + t0) * 256;
#pragma unroll
  for (int it = 0; it < 8; ++it) {
    int lin = it * 256 + tid;
    int r = lin >> 5, cs = (lin & 31) << 3;
    const float* src = sk + (size_t)r * 256 + cs;
    f32x4 a0 = *(const f32x4*)src;
    f32x4 a1v = *(const f32x4*)(src + 4);
    s16x8 v;
#pragma unroll
    for (int j = 0; j < 4; ++j) v[j] = f2bf(fmaxf(a0[j] + sbs[cs + j], 0.f));
#pragma unroll
    for (int j = 0; j < 4; ++j) v[4 + j] = f2bf(fmaxf(a1v[j] + sbs[cs + 4 + j], 0.f));
    *(s16x8*)((char*)sb + swz256(r, cs)) = v;
  }
  __syncthreads();

  // W1 GEMM (M=256,K=256)
  f32x4 a2[4][4] = {};
#pragma unroll
  for (int kb = 0; kb < 8; ++kb) {
    const int icb = kb * 32 + ((lane >> 4) << 3);
    s16x8 bs_[4];
#pragma unroll
    for (int nb = 0; nb < 4; ++nb)
      bs_[nb] = *(const s16x8*)((const char*)sb + swz256(nb * 16 + (lane & 15), icb));
#pragma unroll
    for (int mi = 0; mi < 4; ++mi) {
      s16x8 a = *(const s16x8*)(A1 + ((((4 * w + mi) * 8 + kb) * 64 + lane) << 3));
#pragma unroll
      for (int nb = 0; nb < 4; ++nb) a2[mi][nb] = mfma16(a, bs_[nb], a2[mi][nb]);
    }
  }
  __syncthreads();
#pragma unroll
  for (int mi = 0; mi < 4; ++mi) {
    const int c0 = (4 * w + mi) * 16 + qrow;
#pragma unroll
    for (int nb = 0; nb < 4; ++nb) {
      const int tl = nb * 16 + (lane & 15);
      s16x4 sv;
#pragma unroll
      for (int r = 0; r < 4; ++r)
        sv[r] = f2bf(fmaxf(a2[mi][nb][r] + b1[c0 + r], 0.f));
      *(s16x4*)((char*)sb + swz256(tl, c0)) = sv;
    }
  }
  __syncthreads();

  // W2 GEMM -> out [B][256][T]
  f32x4 a3[4][4] = {};
#pragma unroll
  for (int kb = 0; kb < 8; ++kb) {
    const int icb = kb * 32 + ((lane >> 4) << 3);
    s16x8 bs_[4];
#pragma unroll
    for (int nb = 0; nb < 4; ++nb)
      bs_[nb] = *(const s16x8*)((const char*)sb + swz256(nb * 16 + (lane & 15), icb));
#pragma unroll
    for (int mi = 0; mi < 4; ++mi) {
      s16x8 a = *(const s16x8*)(A2 + ((((4 * w + mi) * 8 + kb) * 64 + lane) << 3));
#pragma unroll
      for (int nb = 0; nb < 4; ++nb) a3[mi][nb] = mfma16(a, bs_[nb], a3[mi][nb]);
    }
  }
#pragma unroll
  for (int mi = 0; mi < 4; ++mi) {
    const int c0 = (4 * w + mi) * 16 + qrow;
#pragma unroll
    for (int nb = 0; nb < 4; ++nb) {
      const int tg = t0 + nb * 16 + (lane & 15);
#pragma unroll
      for (int r = 0; r < 4; ++r)
        out[(size_t)(b * 256 + c0 + r) * 16384 + tg] = a3[mi][nb][r] + b2[c0 + r];
    }
  }
}

// ---------------- host orchestration ---------------------------------------

extern "C" void kernel_launch(void* const* d_in, const int* in_sizes, int n_in,
                              void* d_out, int out_size, void* d_ws, size_t ws_size,
                              hipStream_t stream) {
  (void)in_sizes; (void)n_in;
  const float* x      = (const float*)d_in[0];
  const float* W_init = (const float*)d_in[1];
  const float* b_init = (const float*)d_in[2];
  const float* Wf     = (const float*)d_in[3];
  const float* bf     = (const float*)d_in[4];
  const float* Wg     = (const float*)d_in[5];
  const float* bg     = (const float*)d_in[6];
  const float* Wr     = (const float*)d_in[7];
  const float* br     = (const float*)d_in[8];
  const float* Wsk    = (const float*)d_in[9];
  const float* bs     = (const float*)d_in[10];
  const float* W1     = (const float*)d_in[11];
  const float* b1     = (const float*)d_in[12];
  const float* W2     = (const float*)d_in[13];
  const float* b2     = (const float*)d_in[14];

  // h ping-pong carved out of d_out (134MB; each h is 67MB; dead before final)
  float* h_a = (float*)d_out;
  float* h_b = h_a + (size_t)8 * 16384 * 128;

  char* ws = (char*)d_ws;
  size_t off = 0;
  float* skip = (float*)(ws + off); off += (size_t)8 * 16384 * 256 * 4;     // 134MB
  short* xB   = (short*)(ws + off); off += (size_t)8 * 1024 * 8 * 64 * 8 * 2;// 67MB
  short* Afg  = (short*)(ws + off); off += (size_t)30 * 65536 * 2;
  short* Ar   = (short*)(ws + off); off += (size_t)30 * 16384 * 2;
  short* As   = (short*)(ws + off); off += (size_t)30 * 32768 * 2;
  short* Ai   = (short*)(ws + off); off += (size_t)32768 * 2;
  short* A1   = (short*)(ws + off); off += (size_t)65536 * 2;
  short* A2   = (short*)(ws + off); off += (size_t)65536 * 2;
  float* sbs  = (float*)(ws + off); off += 256 * 4;

  if (ws_size < off) {  // diagnostic: ws still too small (value distinct from R1)
    sentinel_fill<<<(out_size + 255) / 256, 256, 0, stream>>>((float*)d_out, out_size);
    return;
  }

  pack_x<<<16384, 256, 0, stream>>>(x, xB);
  pack_fg<<<7680, 256, 0, stream>>>(Wf, Wg, Afg);
  pack_mats<<<1920, 256, 0, stream>>>(Wr, Ar, 128, 128, 30 * 128 * 128);
  pack_mats<<<3840, 256, 0, stream>>>(Wsk, As, 256, 128, 30 * 256 * 128);
  pack_mats<<<128, 256, 0, stream>>>(W_init, Ai, 128, 256, 128 * 256);
  pack_mats<<<256, 256, 0, stream>>>(W1, A1, 256, 256, 256 * 256);
  pack_mats<<<256, 256, 0, stream>>>(W2, A2, 256, 256, 256 * 256);
  sum_bs_k<<<1, 256, 0, stream>>>(bs, sbs);

  init_kernel<<<2048, 256, 0, stream>>>(xB, Ai, b_init, h_a);

  float* hin = h_a; float* hout = h_b;
  for (int l = 0; l < 30; ++l) {
    int d = 1 << (l % 10);
    layer_kernel<<<2048, 256, 0, stream>>>(hin, hout,
        Afg + (size_t)l * 65536, Ar + (size_t)l * 16384, As + (size_t)l * 32768,
        skip, bf + l * 128, bg + l * 128, br + l * 128, d, l == 0 ? 1 : 0);
    float* tmp = hin; hin = hout; hout = tmp;
  }

  final_kernel<<<2048, 256, 0, stream>>>(skip, A1, A2, sbs, b1, b2, (float*)d_out);
}

// Round 3
// 3891.881 us; speedup vs baseline: 1.2361x; 1.2361x over previous
//
#include <hip/hip_runtime.h>
#include <hip/hip_bf16.h>
#include <stdint.h>

// WaveNet forward, MI355X/gfx950.
// B=8, T=16384, IN=256, RES=128, SKIP=256, L=30, dilations 2^(i%10).
// bf16 MFMA (16x16x32) everywhere, fp32 residual chain, bf16 skip accumulator.
// h ping-pong lives inside d_out (dead before final kernel overwrites it).
// Skip GEMM fused into the layer kernel (bf16 RMW buffer in ws).
// LDS = 32KB: z-tile overlays the prev-tap half of the h tile after FG GEMM.

typedef __attribute__((ext_vector_type(8))) short s16x8;
typedef __attribute__((ext_vector_type(4))) short s16x4;
typedef __attribute__((ext_vector_type(4))) float f32x4;

__device__ __forceinline__ short f2bf(float f) {
  union { float f; uint32_t u; } v; v.f = f;
  uint32_t u = v.u;
  uint32_t r = (u + 0x7FFFu + ((u >> 16) & 1u)) >> 16;   // RNE
  return (short)r;
}
__device__ __forceinline__ float bf2f(short s) {
  union { uint32_t u; float f; } v; v.u = ((uint32_t)(uint16_t)s) << 16;
  return v.f;
}

// XOR-swizzled byte offsets for [rows][128ch] / [rows][256ch] bf16 LDS tiles.
__device__ __forceinline__ int swz128(int row, int c) {
  return row * 256 + ((((c >> 3) ^ (row & 7))) << 4) + ((c & 7) << 1);
}
__device__ __forceinline__ int swz256(int row, int c) {
  return row * 512 + ((((c >> 3) ^ (row & 7))) << 4) + ((c & 7) << 1);
}

// A/B fragment element index for mfma_f32_16x16x32_bf16:
// lane = (m&15) | (((k>>3)&3)<<4), elem j = k&7, frag (mb,kb) contiguous.
__device__ __forceinline__ size_t frag_idx(int m, int k, int K) {
  int lane = (m & 15) | (((k >> 3) & 3) << 4);
  return ((size_t)((m >> 4) * (K >> 5) + (k >> 5)) * 64 + lane) * 8 + (k & 7);
}

__device__ __forceinline__ f32x4 mfma16(s16x8 a, s16x8 b, f32x4 c) {
  return __builtin_amdgcn_mfma_f32_16x16x32_bf16(a, b, c, 0, 0, 0);
}

__device__ __forceinline__ float tanh_f(float x) {
  return 1.f - 2.f / (__expf(2.f * x) + 1.f);
}
__device__ __forceinline__ float sigm_f(float x) {
  return 1.f / (1.f + __expf(-x));
}

// ---------------- packing kernels (run every call; ws is re-poisoned) -------

// x [8][256][16384] fp32 -> B-fragment-packed bf16 [b][nb(1024)][kb(8)][lane][8]
__global__ __launch_bounds__(256) void pack_x(const float* __restrict__ x,
                                              short* __restrict__ xB) {
  size_t i = (size_t)blockIdx.x * 256 + threadIdx.x;   // 4,194,304 total
  int l = (int)(i & 63);
  size_t r = i >> 6;
  int kb = (int)(r & 7); r >>= 3;
  int nb = (int)(r & 1023);
  int b = (int)(r >> 10);
  int t = (nb << 4) + (l & 15);
  int c0 = (kb << 5) + ((l >> 4) << 3);
  const float* xs = x + (size_t)(b * 256 + c0) * 16384 + t;
  s16x8 v;
#pragma unroll
  for (int j = 0; j < 8; ++j) v[j] = f2bf(xs[(size_t)j * 16384]);
  *(s16x8*)(xB + (i << 3)) = v;
}

// Wf,Wg [30][128][128][2] -> stacked A [30][M=256][K=256], k = tap*128 + ic
__global__ __launch_bounds__(256) void pack_fg(const float* __restrict__ Wf,
                                               const float* __restrict__ Wg,
                                               short* __restrict__ A) {
  int i = blockIdx.x * 256 + threadIdx.x;
  if (i >= 30 * 256 * 256) return;
  int l = i >> 16, rem = i & 65535;
  int m = rem >> 8, k = rem & 255;
  int ic = k & 127, tap = k >> 7;
  float v = (m < 128)
      ? Wf[((size_t)(l * 128 + m) * 128 + ic) * 2 + tap]
      : Wg[((size_t)(l * 128 + (m - 128)) * 128 + ic) * 2 + tap];
  A[(size_t)l * 65536 + frag_idx(m, k, 256)] = f2bf(v);
}

// generic [nmat][M][K] fp32 (K-contiguous) -> packed A bf16
__global__ __launch_bounds__(256) void pack_mats(const float* __restrict__ W,
                                                 short* __restrict__ A,
                                                 int M, int K, int total) {
  int i = blockIdx.x * 256 + threadIdx.x;
  if (i >= total) return;
  int mk = M * K;
  int l = i / mk, rem = i - l * mk;
  int m = rem / K, k = rem - m * K;
  A[(size_t)l * mk + frag_idx(m, k, K)] = f2bf(W[i]);
}

__global__ void sum_bs_k(const float* __restrict__ bs, float* __restrict__ sbs) {
  int c = threadIdx.x;
  float s = 0.f;
  for (int l = 0; l < 30; ++l) s += bs[l * 256 + c];
  sbs[c] = s;
}

__global__ __launch_bounds__(256) void sentinel_fill(float* __restrict__ out, int n) {
  int i = blockIdx.x * 256 + threadIdx.x;
  if (i < n) out[i] = -54321.0f;
}

// ---------------- initial 1x1 conv: h0 = W_init x + b_init ------------------

__global__ __launch_bounds__(256) void init_kernel(const short* __restrict__ xB,
                                                   const short* __restrict__ Ai,
                                                   const float* __restrict__ b_init,
                                                   float* __restrict__ h0) {
  const int tid = threadIdx.x, lane = tid & 63, w = tid >> 6;
  const int b = blockIdx.x >> 8, t0 = (blockIdx.x & 255) << 6;
  const short* __restrict__ xb = xB + (size_t)((b << 10) + (t0 >> 4)) * 4096;
  f32x4 acc[2][4] = {};
#pragma unroll
  for (int kb = 0; kb < 8; ++kb) {
    s16x8 bx[4];
#pragma unroll
    for (int nb = 0; nb < 4; ++nb)
      bx[nb] = *(const s16x8*)(xb + (((nb * 8 + kb) * 64 + lane) << 3));
#pragma unroll
    for (int mi = 0; mi < 2; ++mi) {
      s16x8 a = *(const s16x8*)(Ai + ((((2 * w + mi) * 8 + kb) * 64 + lane) << 3));
#pragma unroll
      for (int nb = 0; nb < 4; ++nb) acc[mi][nb] = mfma16(a, bx[nb], acc[mi][nb]);
    }
  }
  const int qrow = (lane >> 4) << 2;
  float* __restrict__ ho = h0 + (size_t)b * 16384 * 128;
#pragma unroll
  for (int mi = 0; mi < 2; ++mi) {
    const int c0 = 32 * w + 16 * mi + qrow;
#pragma unroll
    for (int nb = 0; nb < 4; ++nb) {
      const int tg = t0 + nb * 16 + (lane & 15);
      f32x4 ov;
#pragma unroll
      for (int r = 0; r < 4; ++r) ov[r] = acc[mi][nb][r] + b_init[c0 + r];
      *(f32x4*)(ho + (size_t)tg * 128 + c0) = ov;
    }
  }
}

// ---------------- residual layer (skip fused, bf16 skip RMW) ----------------
// f = tanh(Wf0 h[t-d] + Wf1 h[t] + bf), g = sigm(...), z = f*g
// h_out = h_in + Wr z + br ; skip (+)= Ws z   (bf16 RMW, layer0 plain write)

__global__ __launch_bounds__(256) void layer_kernel(
    const float* __restrict__ h_in, float* __restrict__ h_out,
    const short* __restrict__ Afg, const short* __restrict__ Ar,
    const short* __restrict__ As, short* __restrict__ skip,
    const float* __restrict__ bfv, const float* __restrict__ bgv,
    const float* __restrict__ brv, int d, int first) {
  __shared__ short hl[128 * 128];   // rows 0..63: h[t0-d+r], 64..127: h[t0+r]
  short* zl = hl;                   // z overlays prev-tap half after FG GEMM
  const int tid = threadIdx.x, lane = tid & 63, w = tid >> 6;
  const int b = blockIdx.x >> 8, t0 = (blockIdx.x & 255) << 6;
  const float* __restrict__ hb = h_in + (size_t)b * 16384 * 128;

#pragma unroll
  for (int it = 0; it < 8; ++it) {
    int lin = it * 256 + tid;
    int r = lin >> 4, s = lin & 15;
    int tg = (r < 64) ? (t0 - d + r) : (t0 + r - 64);
    s16x8 v;
    if (tg < 0) {
      v = (s16x8)0;
    } else {
      const float* src = hb + (size_t)tg * 128 + s * 8;
      f32x4 a0 = *(const f32x4*)src;
      f32x4 a1 = *(const f32x4*)(src + 4);
      v[0] = f2bf(a0[0]); v[1] = f2bf(a0[1]); v[2] = f2bf(a0[2]); v[3] = f2bf(a0[3]);
      v[4] = f2bf(a1[0]); v[5] = f2bf(a1[1]); v[6] = f2bf(a1[2]); v[7] = f2bf(a1[3]);
    }
    *(s16x8*)((char*)hl + swz128(r, s * 8)) = v;
  }
  __syncthreads();

  // FG GEMM: M=256 stacked [f;g], K=256 (kb<4: prev-tap rows, kb>=4: cur rows)
  f32x4 acc[4][4] = {};
#pragma unroll
  for (int kb = 0; kb < 8; ++kb) {
    const int rbase = (kb >= 4) ? 64 : 0;
    const int icb = (kb & 3) * 32 + ((lane >> 4) << 3);
    s16x8 bfr[4];
#pragma unroll
    for (int nb = 0; nb < 4; ++nb)
      bfr[nb] = *(const s16x8*)((const char*)hl + swz128(rbase + nb * 16 + (lane & 15), icb));
    s16x8 afr[4];
#pragma unroll
    for (int mi = 0; mi < 4; ++mi) {
      int mb = (mi < 2) ? (2 * w + mi) : (6 + 2 * w + mi);   // f: 2w,2w+1 ; g: 8+2w,8+2w+1
      afr[mi] = *(const s16x8*)(Afg + (((mb * 8 + kb) * 64 + lane) << 3));
    }
#pragma unroll
    for (int mi = 0; mi < 4; ++mi)
#pragma unroll
      for (int nb = 0; nb < 4; ++nb)
        acc[mi][nb] = mfma16(afr[mi], bfr[nb], acc[mi][nb]);
  }
  __syncthreads();   // prev-tap reads done; safe to overlay z

  // gated activation; z -> LDS (overlay)
  const int qrow = (lane >> 4) << 2;
#pragma unroll
  for (int mi = 0; mi < 2; ++mi) {
    const int c0 = 32 * w + 16 * mi + qrow;
#pragma unroll
    for (int nb = 0; nb < 4; ++nb) {
      const int tl = nb * 16 + (lane & 15);
      s16x4 zp;
#pragma unroll
      for (int r = 0; r < 4; ++r) {
        float fv = acc[mi][nb][r] + bfv[c0 + r];
        float gv = acc[mi + 2][nb][r] + bgv[c0 + r];
        zp[r] = f2bf(tanh_f(fv) * sigm_f(gv));
      }
      *(s16x4*)((char*)zl + swz128(tl, c0)) = zp;
    }
  }
  __syncthreads();

  // merged R (M=128) + S (M=256) GEMM over shared z B-fragments, K=128
  f32x4 racc[2][4] = {};
  f32x4 sacc[4][4] = {};
#pragma unroll
  for (int kb = 0; kb < 4; ++kb) {
    const int icb = kb * 32 + ((lane >> 4) << 3);
    s16x8 bz[4];
#pragma unroll
    for (int nb = 0; nb < 4; ++nb)
      bz[nb] = *(const s16x8*)((const char*)zl + swz128(nb * 16 + (lane & 15), icb));
#pragma unroll
    for (int mi = 0; mi < 2; ++mi) {
      s16x8 ar = *(const s16x8*)(Ar + ((((2 * w + mi) * 4 + kb) * 64 + lane) << 3));
#pragma unroll
      for (int nb = 0; nb < 4; ++nb)
        racc[mi][nb] = mfma16(ar, bz[nb], racc[mi][nb]);
    }
#pragma unroll
    for (int mi = 0; mi < 4; ++mi) {
      s16x8 as_ = *(const s16x8*)(As + ((((4 * w + mi) * 4 + kb) * 64 + lane) << 3));
#pragma unroll
      for (int nb = 0; nb < 4; ++nb)
        sacc[mi][nb] = mfma16(as_, bz[nb], sacc[mi][nb]);
    }
  }

  // h_out = h_in + r + br
  float* __restrict__ ho = h_out + (size_t)b * 16384 * 128;
#pragma unroll
  for (int mi = 0; mi < 2; ++mi) {
    const int c0 = 32 * w + 16 * mi + qrow;
#pragma unroll
    for (int nb = 0; nb < 4; ++nb) {
      const int tg = t0 + nb * 16 + (lane & 15);
      f32x4 hv = *(const f32x4*)(hb + (size_t)tg * 128 + c0);
      f32x4 ov;
#pragma unroll
      for (int r = 0; r < 4; ++r) ov[r] = hv[r] + racc[mi][nb][r] + brv[c0 + r];
      *(f32x4*)(ho + (size_t)tg * 128 + c0) = ov;
    }
  }

  // skip accumulate (bf16 RMW). layer0: plain write.
  short* __restrict__ sk = skip + ((size_t)b * 16384 + t0) * 256;
#pragma unroll
  for (int mi = 0; mi < 4; ++mi) {
    const int c0 = (4 * w + mi) * 16 + qrow;
#pragma unroll
    for (int nb = 0; nb < 4; ++nb) {
      const int tl = nb * 16 + (lane & 15);
      short* sp = sk + (size_t)tl * 256 + c0;
      s16x4 ov;
      if (first) {
#pragma unroll
        for (int r = 0; r < 4; ++r) ov[r] = f2bf(sacc[mi][nb][r]);
      } else {
        s16x4 sv = *(const s16x4*)sp;
#pragma unroll
        for (int r = 0; r < 4; ++r) ov[r] = f2bf(bf2f(sv[r]) + sacc[mi][nb][r]);
      }
      *(s16x4*)sp = ov;
    }
  }
}

// ---------------- final: relu(skip+sbs) -> W1 -> relu -> W2 -> out ----------

__global__ __launch_bounds__(256) void final_kernel(
    const short* __restrict__ skip, const short* __restrict__ A1,
    const short* __restrict__ A2, const float* __restrict__ sbs,
    const float* __restrict__ b1, const float* __restrict__ b2,
    float* __restrict__ out) {
  __shared__ short sb[64 * 256];
  const int tid = threadIdx.x, lane = tid & 63, w = tid >> 6;
  const int b = blockIdx.x >> 8, t0 = (blockIdx.x & 255) << 6;
  const int qrow = (lane >> 4) << 2;

  // stage relu(skip + sbs) -> sb (bf16, swizzled)
  const short* __restrict__ sk = skip + ((size_t)b * 16384 + t0) * 256;
#pragma unroll
  for (int it = 0; it < 8; ++it) {
    int lin = it * 256 + tid;
    int r = lin >> 5, cs = (lin & 31) << 3;
    s16x8 sv = *(const s16x8*)(sk + (size_t)r * 256 + cs);
    s16x8 v;
#pragma unroll
    for (int j = 0; j < 8; ++j) v[j] = f2bf(fmaxf(bf2f(sv[j]) + sbs[cs + j], 0.f));
    *(s16x8*)((char*)sb + swz256(r, cs)) = v;
  }
  __syncthreads();

  // W1 GEMM (M=256,K=256)
  f32x4 a2[4][4] = {};
#pragma unroll
  for (int kb = 0; kb < 8; ++kb) {
    const int icb = kb * 32 + ((lane >> 4) << 3);
    s16x8 bs_[4];
#pragma unroll
    for (int nb = 0; nb < 4; ++nb)
      bs_[nb] = *(const s16x8*)((const char*)sb + swz256(nb * 16 + (lane & 15), icb));
#pragma unroll
    for (int mi = 0; mi < 4; ++mi) {
      s16x8 a = *(const s16x8*)(A1 + ((((4 * w + mi) * 8 + kb) * 64 + lane) << 3));
#pragma unroll
      for (int nb = 0; nb < 4; ++nb) a2[mi][nb] = mfma16(a, bs_[nb], a2[mi][nb]);
    }
  }
  __syncthreads();
#pragma unroll
  for (int mi = 0; mi < 4; ++mi) {
    const int c0 = (4 * w + mi) * 16 + qrow;
#pragma unroll
    for (int nb = 0; nb < 4; ++nb) {
      const int tl = nb * 16 + (lane & 15);
      s16x4 sv;
#pragma unroll
      for (int r = 0; r < 4; ++r)
        sv[r] = f2bf(fmaxf(a2[mi][nb][r] + b1[c0 + r], 0.f));
      *(s16x4*)((char*)sb + swz256(tl, c0)) = sv;
    }
  }
  __syncthreads();

  // W2 GEMM -> out [B][256][T]
  f32x4 a3[4][4] = {};
#pragma unroll
  for (int kb = 0; kb < 8; ++kb) {
    const int icb = kb * 32 + ((lane >> 4) << 3);
    s16x8 bs_[4];
#pragma unroll
    for (int nb = 0; nb < 4; ++nb)
      bs_[nb] = *(const s16x8*)((const char*)sb + swz256(nb * 16 + (lane & 15), icb));
#pragma unroll
    for (int mi = 0; mi < 4; ++mi) {
      s16x8 a = *(const s16x8*)(A2 + ((((4 * w + mi) * 8 + kb) * 64 + lane) << 3));
#pragma unroll
      for (int nb = 0; nb < 4; ++nb) a3[mi][nb] = mfma16(a, bs_[nb], a3[mi][nb]);
    }
  }
#pragma unroll
  for (int mi = 0; mi < 4; ++mi) {
    const int c0 = (4 * w + mi) * 16 + qrow;
#pragma unroll
    for (int nb = 0; nb < 4; ++nb) {
      const int tg = t0 + nb * 16 + (lane & 15);
#pragma unroll
      for (int r = 0; r < 4; ++r)
        out[(size_t)(b * 256 + c0 + r) * 16384 + tg] = a3[mi][nb][r] + b2[c0 + r];
    }
  }
}

// ---------------- host orchestration ---------------------------------------

extern "C" void kernel_launch(void* const* d_in, const int* in_sizes, int n_in,
                              void* d_out, int out_size, void* d_ws, size_t ws_size,
                              hipStream_t stream) {
  (void)in_sizes; (void)n_in;
  const float* x      = (const float*)d_in[0];
  const float* W_init = (const float*)d_in[1];
  const float* b_init = (const float*)d_in[2];
  const float* Wf     = (const float*)d_in[3];
  const float* bf     = (const float*)d_in[4];
  const float* Wg     = (const float*)d_in[5];
  const float* bg     = (const float*)d_in[6];
  const float* Wr     = (const float*)d_in[7];
  const float* br     = (const float*)d_in[8];
  const float* Wsk    = (const float*)d_in[9];
  const float* bs     = (const float*)d_in[10];
  const float* W1     = (const float*)d_in[11];
  const float* b1     = (const float*)d_in[12];
  const float* W2     = (const float*)d_in[13];
  const float* b2     = (const float*)d_in[14];

  // h ping-pong carved out of d_out (134MB; each h is 67MB; dead before final)
  float* h_a = (float*)d_out;
  float* h_b = h_a + (size_t)8 * 16384 * 128;

  char* ws = (char*)d_ws;
  size_t off = 0;
  short* skip = (short*)(ws + off); off += (size_t)8 * 16384 * 256 * 2;      // 67MB
  short* xB   = (short*)(ws + off); off += (size_t)8 * 1024 * 8 * 64 * 8 * 2;// 67MB
  short* Afg  = (short*)(ws + off); off += (size_t)30 * 65536 * 2;
  short* Ar   = (short*)(ws + off); off += (size_t)30 * 16384 * 2;
  short* As   = (short*)(ws + off); off += (size_t)30 * 32768 * 2;
  short* Ai   = (short*)(ws + off); off += (size_t)32768 * 2;
  short* A1   = (short*)(ws + off); off += (size_t)65536 * 2;
  short* A2   = (short*)(ws + off); off += (size_t)65536 * 2;
  float* sbs  = (float*)(ws + off); off += 256 * 4;

  if (ws_size < off) {
    sentinel_fill<<<(out_size + 255) / 256, 256, 0, stream>>>((float*)d_out, out_size);
    return;
  }

  pack_x<<<16384, 256, 0, stream>>>(x, xB);
  pack_fg<<<7680, 256, 0, stream>>>(Wf, Wg, Afg);
  pack_mats<<<1920, 256, 0, stream>>>(Wr, Ar, 128, 128, 30 * 128 * 128);
  pack_mats<<<3840, 256, 0, stream>>>(Wsk, As, 256, 128, 30 * 256 * 128);
  pack_mats<<<128, 256, 0, stream>>>(W_init, Ai, 128, 256, 128 * 256);
  pack_mats<<<256, 256, 0, stream>>>(W1, A1, 256, 256, 256 * 256);
  pack_mats<<<256, 256, 0, stream>>>(W2, A2, 256, 256, 256 * 256);
  sum_bs_k<<<1, 256, 0, stream>>>(bs, sbs);

  init_kernel<<<2048, 256, 0, stream>>>(xB, Ai, b_init, h_a);

  float* hin = h_a; float* hout = h_b;
  for (int l = 0; l < 30; ++l) {
    int d = 1 << (l % 10);
    layer_kernel<<<2048, 256, 0, stream>>>(hin, hout,
        Afg + (size_t)l * 65536, Ar + (size_t)l * 16384, As + (size_t)l * 32768,
        skip, bf + l * 128, bg + l * 128, br + l * 128, d, l == 0 ? 1 : 0);
    float* tmp = hin; hin = hout; hout = tmp;
  }

  final_kernel<<<2048, 256, 0, stream>>>(skip, A1, A2, sbs, b1, b2, (float*)d_out);
}

// Round 4
// 3636.305 us; speedup vs baseline: 1.3230x; 1.0703x over previous
//
#include <hip/hip_runtime.h>
#include <hip/hip_bf16.h>
#include <stdint.h>

// WaveNet forward, MI355X/gfx950.
// B=8, T=16384, IN=256, RES=128, SKIP=256, L=30, dilations 2^(i%10).
// bf16 MFMA (16x16x32) everywhere, fp32 residual chain, bf16 skip accumulator.
// h ping-pong lives inside d_out; skip GEMM fused into the layer kernel.
// Round 4: LDS-bounce epilogues -> all global reads/writes row-contiguous.

typedef __attribute__((ext_vector_type(8))) short s16x8;
typedef __attribute__((ext_vector_type(4))) short s16x4;
typedef __attribute__((ext_vector_type(4))) float f32x4;

__device__ __forceinline__ short f2bf(float f) {
  union { float f; uint32_t u; } v; v.f = f;
  uint32_t u = v.u;
  uint32_t r = (u + 0x7FFFu + ((u >> 16) & 1u)) >> 16;   // RNE
  return (short)r;
}
__device__ __forceinline__ float bf2f(short s) {
  union { uint32_t u; float f; } v; v.u = ((uint32_t)(uint16_t)s) << 16;
  return v.f;
}

// XOR-swizzled byte offsets, 16B slots XOR'd with row&7 (512B-row tiles).
__device__ __forceinline__ int swz128(int row, int c) {   // [rows][128] bf16
  return row * 256 + ((((c >> 3) ^ (row & 7))) << 4) + ((c & 7) << 1);
}
__device__ __forceinline__ int swz256(int row, int c) {   // [rows][256] bf16
  return row * 512 + ((((c >> 3) ^ (row & 7))) << 4) + ((c & 7) << 1);
}
__device__ __forceinline__ int swzf128(int row, int c) {  // [rows][128] f32
  return row * 512 + ((((c >> 2) ^ (row & 7))) << 4);     // c multiple of 4
}

// A/B fragment element index for mfma_f32_16x16x32_bf16.
__device__ __forceinline__ size_t frag_idx(int m, int k, int K) {
  int lane = (m & 15) | (((k >> 3) & 3) << 4);
  return ((size_t)((m >> 4) * (K >> 5) + (k >> 5)) * 64 + lane) * 8 + (k & 7);
}

__device__ __forceinline__ f32x4 mfma16(s16x8 a, s16x8 b, f32x4 c) {
  return __builtin_amdgcn_mfma_f32_16x16x32_bf16(a, b, c, 0, 0, 0);
}

__device__ __forceinline__ float tanh_f(float x) {
  return 1.f - 2.f / (__expf(2.f * x) + 1.f);
}
__device__ __forceinline__ float sigm_f(float x) {
  return 1.f / (1.f + __expf(-x));
}

// ---------------- packing kernels (run every call; ws is re-poisoned) -------

__global__ __launch_bounds__(256) void pack_x(const float* __restrict__ x,
                                              short* __restrict__ xB) {
  size_t i = (size_t)blockIdx.x * 256 + threadIdx.x;   // 4,194,304 total
  int l = (int)(i & 63);
  size_t r = i >> 6;
  int kb = (int)(r & 7); r >>= 3;
  int nb = (int)(r & 1023);
  int b = (int)(r >> 10);
  int t = (nb << 4) + (l & 15);
  int c0 = (kb << 5) + ((l >> 4) << 3);
  const float* xs = x + (size_t)(b * 256 + c0) * 16384 + t;
  s16x8 v;
#pragma unroll
  for (int j = 0; j < 8; ++j) v[j] = f2bf(xs[(size_t)j * 16384]);
  *(s16x8*)(xB + (i << 3)) = v;
}

__global__ __launch_bounds__(256) void pack_fg(const float* __restrict__ Wf,
                                               const float* __restrict__ Wg,
                                               short* __restrict__ A) {
  int i = blockIdx.x * 256 + threadIdx.x;
  if (i >= 30 * 256 * 256) return;
  int l = i >> 16, rem = i & 65535;
  int m = rem >> 8, k = rem & 255;
  int ic = k & 127, tap = k >> 7;
  float v = (m < 128)
      ? Wf[((size_t)(l * 128 + m) * 128 + ic) * 2 + tap]
      : Wg[((size_t)(l * 128 + (m - 128)) * 128 + ic) * 2 + tap];
  A[(size_t)l * 65536 + frag_idx(m, k, 256)] = f2bf(v);
}

__global__ __launch_bounds__(256) void pack_mats(const float* __restrict__ W,
                                                 short* __restrict__ A,
                                                 int M, int K, int total) {
  int i = blockIdx.x * 256 + threadIdx.x;
  if (i >= total) return;
  int mk = M * K;
  int l = i / mk, rem = i - l * mk;
  int m = rem / K, k = rem - m * K;
  A[(size_t)l * mk + frag_idx(m, k, K)] = f2bf(W[i]);
}

__global__ void sum_bs_k(const float* __restrict__ bs, float* __restrict__ sbs) {
  int c = threadIdx.x;
  float s = 0.f;
  for (int l = 0; l < 30; ++l) s += bs[l * 256 + c];
  sbs[c] = s;
}

__global__ __launch_bounds__(256) void sentinel_fill(float* __restrict__ out, int n) {
  int i = blockIdx.x * 256 + threadIdx.x;
  if (i < n) out[i] = -54321.0f;
}

// ---------------- initial 1x1 conv: h0 = W_init x + b_init ------------------

__global__ __launch_bounds__(256) void init_kernel(const short* __restrict__ xB,
                                                   const short* __restrict__ Ai,
                                                   const float* __restrict__ b_init,
                                                   float* __restrict__ h0) {
  __shared__ float rl[64 * 128];
  const int tid = threadIdx.x, lane = tid & 63, w = tid >> 6;
  const int b = blockIdx.x >> 8, t0 = (blockIdx.x & 255) << 6;
  const short* __restrict__ xb = xB + (size_t)((b << 10) + (t0 >> 4)) * 4096;
  f32x4 acc[2][4] = {};
#pragma unroll
  for (int kb = 0; kb < 8; ++kb) {
    s16x8 bx[4];
#pragma unroll
    for (int nb = 0; nb < 4; ++nb)
      bx[nb] = *(const s16x8*)(xb + (((nb * 8 + kb) * 64 + lane) << 3));
#pragma unroll
    for (int mi = 0; mi < 2; ++mi) {
      s16x8 a = *(const s16x8*)(Ai + ((((2 * w + mi) * 8 + kb) * 64 + lane) << 3));
#pragma unroll
      for (int nb = 0; nb < 4; ++nb) acc[mi][nb] = mfma16(a, bx[nb], acc[mi][nb]);
    }
  }
  const int qrow = (lane >> 4) << 2;
#pragma unroll
  for (int mi = 0; mi < 2; ++mi) {
    const int c0 = 32 * w + 16 * mi + qrow;
#pragma unroll
    for (int nb = 0; nb < 4; ++nb) {
      const int tl = nb * 16 + (lane & 15);
      *(f32x4*)((char*)rl + swzf128(tl, c0)) = acc[mi][nb];
    }
  }
  __syncthreads();
  float* __restrict__ ho = h0 + ((size_t)b * 16384 + t0) * 128;
#pragma unroll
  for (int it = 0; it < 8; ++it) {
    int lin = it * 256 + tid;
    int row = lin >> 5, sl = lin & 31;
    f32x4 rv = *(const f32x4*)((char*)rl + swzf128(row, sl * 4));
    f32x4 ov;
#pragma unroll
    for (int j = 0; j < 4; ++j) ov[j] = rv[j] + b_init[sl * 4 + j];
    *(f32x4*)(ho + (size_t)row * 128 + sl * 4) = ov;
  }
}

// ---------------- residual layer (skip fused, LDS-bounce epilogues) ---------
// f = tanh(Wf0 h[t-d] + Wf1 h[t] + bf), g = sigm(...), z = f*g
// h_out = h_in + Wr z + br ; skip (+)= Ws z   (bf16 RMW, layer0 plain write)

__global__ __launch_bounds__(256) void layer_kernel(
    const float* __restrict__ h_in, float* __restrict__ h_out,
    const short* __restrict__ Afg, const short* __restrict__ Ar,
    const short* __restrict__ As, short* __restrict__ skip,
    const float* __restrict__ bfv, const float* __restrict__ bgv,
    const float* __restrict__ brv, int d, int first) {
  __shared__ short hl[128 * 128];   // rows 0..63: h[t0-d+r], 64..127: h[t0+r]
  short* zl = hl;                   // z overlays prev-tap half after FG GEMM
  const int tid = threadIdx.x, lane = tid & 63, w = tid >> 6;
  const int b = blockIdx.x >> 8, t0 = (blockIdx.x & 255) << 6;
  const float* __restrict__ hb = h_in + (size_t)b * 16384 * 128;

#pragma unroll
  for (int it = 0; it < 8; ++it) {
    int lin = it * 256 + tid;
    int r = lin >> 4, s = lin & 15;
    int tg = (r < 64) ? (t0 - d + r) : (t0 + r - 64);
    s16x8 v;
    if (tg < 0) {
      v = (s16x8)0;
    } else {
      const float* src = hb + (size_t)tg * 128 + s * 8;
      f32x4 a0 = *(const f32x4*)src;
      f32x4 a1 = *(const f32x4*)(src + 4);
      v[0] = f2bf(a0[0]); v[1] = f2bf(a0[1]); v[2] = f2bf(a0[2]); v[3] = f2bf(a0[3]);
      v[4] = f2bf(a1[0]); v[5] = f2bf(a1[1]); v[6] = f2bf(a1[2]); v[7] = f2bf(a1[3]);
    }
    *(s16x8*)((char*)hl + swz128(r, s * 8)) = v;
  }
  __syncthreads();

  // FG GEMM: M=256 stacked [f;g], K=256 (kb<4: prev-tap rows, kb>=4: cur rows)
  f32x4 acc[4][4] = {};
#pragma unroll
  for (int kb = 0; kb < 8; ++kb) {
    const int rbase = (kb >= 4) ? 64 : 0;
    const int icb = (kb & 3) * 32 + ((lane >> 4) << 3);
    s16x8 bfr[4];
#pragma unroll
    for (int nb = 0; nb < 4; ++nb)
      bfr[nb] = *(const s16x8*)((const char*)hl + swz128(rbase + nb * 16 + (lane & 15), icb));
    s16x8 afr[4];
#pragma unroll
    for (int mi = 0; mi < 4; ++mi) {
      int mb = (mi < 2) ? (2 * w + mi) : (6 + 2 * w + mi);   // f: 2w,2w+1 ; g: 8+2w,8+2w+1
      afr[mi] = *(const s16x8*)(Afg + (((mb * 8 + kb) * 64 + lane) << 3));
    }
#pragma unroll
    for (int mi = 0; mi < 4; ++mi)
#pragma unroll
      for (int nb = 0; nb < 4; ++nb)
        acc[mi][nb] = mfma16(afr[mi], bfr[nb], acc[mi][nb]);
  }
  __syncthreads();   // prev-tap reads done; safe to overlay z

  // gated activation; z -> LDS (overlay)
  const int qrow = (lane >> 4) << 2;
#pragma unroll
  for (int mi = 0; mi < 2; ++mi) {
    const int c0 = 32 * w + 16 * mi + qrow;
#pragma unroll
    for (int nb = 0; nb < 4; ++nb) {
      const int tl = nb * 16 + (lane & 15);
      s16x4 zp;
#pragma unroll
      for (int r = 0; r < 4; ++r) {
        float fv = acc[mi][nb][r] + bfv[c0 + r];
        float gv = acc[mi + 2][nb][r] + bgv[c0 + r];
        zp[r] = f2bf(tanh_f(fv) * sigm_f(gv));
      }
      *(s16x4*)((char*)zl + swz128(tl, c0)) = zp;
    }
  }
  __syncthreads();

  // merged R (M=128) + S (M=256) GEMM over shared z B-fragments, K=128
  f32x4 racc[2][4] = {};
  f32x4 sacc[4][4] = {};
#pragma unroll
  for (int kb = 0; kb < 4; ++kb) {
    const int icb = kb * 32 + ((lane >> 4) << 3);
    s16x8 bz[4];
#pragma unroll
    for (int nb = 0; nb < 4; ++nb)
      bz[nb] = *(const s16x8*)((const char*)zl + swz128(nb * 16 + (lane & 15), icb));
#pragma unroll
    for (int mi = 0; mi < 2; ++mi) {
      s16x8 ar = *(const s16x8*)(Ar + ((((2 * w + mi) * 4 + kb) * 64 + lane) << 3));
#pragma unroll
      for (int nb = 0; nb < 4; ++nb)
        racc[mi][nb] = mfma16(ar, bz[nb], racc[mi][nb]);
    }
#pragma unroll
    for (int mi = 0; mi < 4; ++mi) {
      s16x8 as_ = *(const s16x8*)(As + ((((4 * w + mi) * 4 + kb) * 64 + lane) << 3));
#pragma unroll
      for (int nb = 0; nb < 4; ++nb)
        sacc[mi][nb] = mfma16(as_, bz[nb], sacc[mi][nb]);
    }
  }
  __syncthreads();   // zl reads done; reuse hl as f32 r-tile

  // racc -> LDS f32 [64][128]
  float* rl = (float*)hl;
#pragma unroll
  for (int mi = 0; mi < 2; ++mi) {
    const int c0 = 32 * w + 16 * mi + qrow;
#pragma unroll
    for (int nb = 0; nb < 4; ++nb) {
      const int tl = nb * 16 + (lane & 15);
      *(f32x4*)((char*)rl + swzf128(tl, c0)) = racc[mi][nb];
    }
  }
  __syncthreads();

  // coalesced h_out = h_in + r + br   (h_in rows t0.. are L2-hot from staging)
  {
    const float* __restrict__ hi = hb + (size_t)t0 * 128;
    float* __restrict__ ho = h_out + ((size_t)b * 16384 + t0) * 128;
#pragma unroll
    for (int it = 0; it < 8; ++it) {
      int lin = it * 256 + tid;
      int row = lin >> 5, sl = lin & 31;
      f32x4 rv = *(const f32x4*)((char*)rl + swzf128(row, sl * 4));
      f32x4 hv = *(const f32x4*)(hi + (size_t)row * 128 + sl * 4);
      f32x4 ov;
#pragma unroll
      for (int j = 0; j < 4; ++j) ov[j] = hv[j] + rv[j] + brv[sl * 4 + j];
      *(f32x4*)(ho + (size_t)row * 128 + sl * 4) = ov;
    }
  }
  __syncthreads();   // rl reads done; reuse hl as bf16 skip tile

  // sacc -> LDS bf16 [64][256]
#pragma unroll
  for (int mi = 0; mi < 4; ++mi) {
    const int c0 = (4 * w + mi) * 16 + qrow;
#pragma unroll
    for (int nb = 0; nb < 4; ++nb) {
      const int tl = nb * 16 + (lane & 15);
      s16x4 sv;
#pragma unroll
      for (int r = 0; r < 4; ++r) sv[r] = f2bf(sacc[mi][nb][r]);
      *(s16x4*)((char*)hl + swz256(tl, c0)) = sv;
    }
  }
  __syncthreads();

  // coalesced skip RMW (bf16). layer0: plain write.
  {
    short* __restrict__ sk = skip + ((size_t)b * 16384 + t0) * 256;
#pragma unroll
    for (int it = 0; it < 8; ++it) {
      int lin = it * 256 + tid;
      int row = lin >> 5, sl = lin & 31;
      s16x8 zv = *(const s16x8*)((char*)hl + swz256(row, sl * 8));
      short* sp = sk + (size_t)row * 256 + sl * 8;
      s16x8 ov;
      if (first) {
        ov = zv;
      } else {
        s16x8 pv = *(const s16x8*)sp;
#pragma unroll
        for (int j = 0; j < 8; ++j) ov[j] = f2bf(bf2f(pv[j]) + bf2f(zv[j]));
      }
      *(s16x8*)sp = ov;
    }
  }
}

// ---------------- final: relu(skip+sbs) -> W1 -> relu -> W2 -> out ----------

__global__ __launch_bounds__(256) void final_kernel(
    const short* __restrict__ skip, const short* __restrict__ A1,
    const short* __restrict__ A2, const float* __restrict__ sbs,
    const float* __restrict__ b1, const float* __restrict__ b2,
    float* __restrict__ out) {
  __shared__ short sb[64 * 256];
  const int tid = threadIdx.x, lane = tid & 63, w = tid >> 6;
  const int b = blockIdx.x >> 8, t0 = (blockIdx.x & 255) << 6;
  const int qrow = (lane >> 4) << 2;

  // stage relu(skip + sbs) -> sb (bf16, swizzled)
  const short* __restrict__ sk = skip + ((size_t)b * 16384 + t0) * 256;
#pragma unroll
  for (int it = 0; it < 8; ++it) {
    int lin = it * 256 + tid;
    int r = lin >> 5, cs = (lin & 31) << 3;
    s16x8 sv = *(const s16x8*)(sk + (size_t)r * 256 + cs);
    s16x8 v;
#pragma unroll
    for (int j = 0; j < 8; ++j) v[j] = f2bf(fmaxf(bf2f(sv[j]) + sbs[cs + j], 0.f));
    *(s16x8*)((char*)sb + swz256(r, cs)) = v;
  }
  __syncthreads();

  // W1 GEMM (M=256,K=256)
  f32x4 a2[4][4] = {};
#pragma unroll
  for (int kb = 0; kb < 8; ++kb) {
    const int icb = kb * 32 + ((lane >> 4) << 3);
    s16x8 bs_[4];
#pragma unroll
    for (int nb = 0; nb < 4; ++nb)
      bs_[nb] = *(const s16x8*)((const char*)sb + swz256(nb * 16 + (lane & 15), icb));
#pragma unroll
    for (int mi = 0; mi < 4; ++mi) {
      s16x8 a = *(const s16x8*)(A1 + ((((4 * w + mi) * 8 + kb) * 64 + lane) << 3));
#pragma unroll
      for (int nb = 0; nb < 4; ++nb) a2[mi][nb] = mfma16(a, bs_[nb], a2[mi][nb]);
    }
  }
  __syncthreads();
#pragma unroll
  for (int mi = 0; mi < 4; ++mi) {
    const int c0 = (4 * w + mi) * 16 + qrow;
#pragma unroll
    for (int nb = 0; nb < 4; ++nb) {
      const int tl = nb * 16 + (lane & 15);
      s16x4 sv;
#pragma unroll
      for (int r = 0; r < 4; ++r)
        sv[r] = f2bf(fmaxf(a2[mi][nb][r] + b1[c0 + r], 0.f));
      *(s16x4*)((char*)sb + swz256(tl, c0)) = sv;
    }
  }
  __syncthreads();

  // W2 GEMM -> out [B][256][T]
  f32x4 a3[4][4] = {};
#pragma unroll
  for (int kb = 0; kb < 8; ++kb) {
    const int icb = kb * 32 + ((lane >> 4) << 3);
    s16x8 bs_[4];
#pragma unroll
    for (int nb = 0; nb < 4; ++nb)
      bs_[nb] = *(const s16x8*)((const char*)sb + swz256(nb * 16 + (lane & 15), icb));
#pragma unroll
    for (int mi = 0; mi < 4; ++mi) {
      s16x8 a = *(const s16x8*)(A2 + ((((4 * w + mi) * 8 + kb) * 64 + lane) << 3));
#pragma unroll
      for (int nb = 0; nb < 4; ++nb) a3[mi][nb] = mfma16(a, bs_[nb], a3[mi][nb]);
    }
  }
#pragma unroll
  for (int mi = 0; mi < 4; ++mi) {
    const int c0 = (4 * w + mi) * 16 + qrow;
#pragma unroll
    for (int nb = 0; nb < 4; ++nb) {
      const int tg = t0 + nb * 16 + (lane & 15);
#pragma unroll
      for (int r = 0; r < 4; ++r)
        out[(size_t)(b * 256 + c0 + r) * 16384 + tg] = a3[mi][nb][r] + b2[c0 + r];
    }
  }
}

// ---------------- host orchestration ---------------------------------------

extern "C" void kernel_launch(void* const* d_in, const int* in_sizes, int n_in,
                              void* d_out, int out_size, void* d_ws, size_t ws_size,
                              hipStream_t stream) {
  (void)in_sizes; (void)n_in;
  const float* x      = (const float*)d_in[0];
  const float* W_init = (const float*)d_in[1];
  const float* b_init = (const float*)d_in[2];
  const float* Wf     = (const float*)d_in[3];
  const float* bf     = (const float*)d_in[4];
  const float* Wg     = (const float*)d_in[5];
  const float* bg     = (const float*)d_in[6];
  const float* Wr     = (const float*)d_in[7];
  const float* br     = (const float*)d_in[8];
  const float* Wsk    = (const float*)d_in[9];
  const float* bs     = (const float*)d_in[10];
  const float* W1     = (const float*)d_in[11];
  const float* b1     = (const float*)d_in[12];
  const float* W2     = (const float*)d_in[13];
  const float* b2     = (const float*)d_in[14];

  // h ping-pong carved out of d_out (134MB; each h is 67MB; dead before final)
  float* h_a = (float*)d_out;
  float* h_b = h_a + (size_t)8 * 16384 * 128;

  char* ws = (char*)d_ws;
  size_t off = 0;
  short* skip = (short*)(ws + off); off += (size_t)8 * 16384 * 256 * 2;      // 67MB
  short* xB   = (short*)(ws + off); off += (size_t)8 * 1024 * 8 * 64 * 8 * 2;// 67MB
  short* Afg  = (short*)(ws + off); off += (size_t)30 * 65536 * 2;
  short* Ar   = (short*)(ws + off); off += (size_t)30 * 16384 * 2;
  short* As   = (short*)(ws + off); off += (size_t)30 * 32768 * 2;
  short* Ai   = (short*)(ws + off); off += (size_t)32768 * 2;
  short* A1   = (short*)(ws + off); off += (size_t)65536 * 2;
  short* A2   = (short*)(ws + off); off += (size_t)65536 * 2;
  float* sbs  = (float*)(ws + off); off += 256 * 4;

  if (ws_size < off) {
    sentinel_fill<<<(out_size + 255) / 256, 256, 0, stream>>>((float*)d_out, out_size);
    return;
  }

  pack_x<<<16384, 256, 0, stream>>>(x, xB);
  pack_fg<<<7680, 256, 0, stream>>>(Wf, Wg, Afg);
  pack_mats<<<1920, 256, 0, stream>>>(Wr, Ar, 128, 128, 30 * 128 * 128);
  pack_mats<<<3840, 256, 0, stream>>>(Wsk, As, 256, 128, 30 * 256 * 128);
  pack_mats<<<128, 256, 0, stream>>>(W_init, Ai, 128, 256, 128 * 256);
  pack_mats<<<256, 256, 0, stream>>>(W1, A1, 256, 256, 256 * 256);
  pack_mats<<<256, 256, 0, stream>>>(W2, A2, 256, 256, 256 * 256);
  sum_bs_k<<<1, 256, 0, stream>>>(bs, sbs);

  init_kernel<<<2048, 256, 0, stream>>>(xB, Ai, b_init, h_a);

  float* hin = h_a; float* hout = h_b;
  for (int l = 0; l < 30; ++l) {
    int d = 1 << (l % 10);
    layer_kernel<<<2048, 256, 0, stream>>>(hin, hout,
        Afg + (size_t)l * 65536, Ar + (size_t)l * 16384, As + (size_t)l * 32768,
        skip, bf + l * 128, bg + l * 128, br + l * 128, d, l == 0 ? 1 : 0);
    float* tmp = hin; hin = hout; hout = tmp;
  }

  final_kernel<<<2048, 256, 0, stream>>>(skip, A1, A2, sbs, b1, b2, (float*)d_out);
}

// Round 5
// 2760.703 us; speedup vs baseline: 1.7426x; 1.3172x over previous
//
#include <hip/hip_runtime.h>
#include <hip/hip_bf16.h>
#include <stdint.h>

// WaveNet forward, MI355X/gfx950.
// B=8, T=16384, IN=256, RES=128, SKIP=256, L=30, dilations 2^(i%10).
// bf16 MFMA (16x16x32), fp32 residual chain, bf16 skip accumulator.
// Round 5: 512-thread layer blocks (8 waves), v_cvt_pk_bf16_f32 + v_rcp_f32
// for VALU-light conversions/activations, skip-tile register prefetch,
// h_in kept in regs for the residual epilogue (no global re-read).

typedef __attribute__((ext_vector_type(8))) short s16x8;
typedef __attribute__((ext_vector_type(4))) short s16x4;
typedef __attribute__((ext_vector_type(4))) float f32x4;

__device__ __forceinline__ short f2bf(float f) {
  union { float f; uint32_t u; } v; v.f = f;
  uint32_t u = v.u;
  uint32_t r = (u + 0x7FFFu + ((u >> 16) & 1u)) >> 16;   // RNE
  return (short)r;
}
__device__ __forceinline__ float bf2f(short s) {
  union { uint32_t u; float f; } v; v.u = ((uint32_t)(uint16_t)s) << 16;
  return v.f;
}
// packed f32x2 -> bf16x2 (RNE), lo in low 16 bits
__device__ __forceinline__ uint32_t cvtpk(float lo, float hi) {
  uint32_t r;
  asm("v_cvt_pk_bf16_f32 %0, %1, %2" : "=v"(r) : "v"(lo), "v"(hi));
  return r;
}
__device__ __forceinline__ float fast_rcp(float x) {
  float r;
  asm("v_rcp_f32 %0, %1" : "=v"(r) : "v"(x));
  return r;
}

// XOR-swizzled byte offsets, 16B slots XOR'd with row&7 (512B-row tiles).
__device__ __forceinline__ int swz128(int row, int c) {   // [rows][128] bf16
  return row * 256 + ((((c >> 3) ^ (row & 7))) << 4) + ((c & 7) << 1);
}
__device__ __forceinline__ int swz256(int row, int c) {   // [rows][256] bf16
  return row * 512 + ((((c >> 3) ^ (row & 7))) << 4) + ((c & 7) << 1);
}
__device__ __forceinline__ int swzf128(int row, int c) {  // [rows][128] f32
  return row * 512 + ((((c >> 2) ^ (row & 7))) << 4);     // c multiple of 4
}

// A/B fragment element index for mfma_f32_16x16x32_bf16.
__device__ __forceinline__ size_t frag_idx(int m, int k, int K) {
  int lane = (m & 15) | (((k >> 3) & 3) << 4);
  return ((size_t)((m >> 4) * (K >> 5) + (k >> 5)) * 64 + lane) * 8 + (k & 7);
}

__device__ __forceinline__ f32x4 mfma16(s16x8 a, s16x8 b, f32x4 c) {
  return __builtin_amdgcn_mfma_f32_16x16x32_bf16(a, b, c, 0, 0, 0);
}

// ---------------- packing kernels (run every call; ws is re-poisoned) -------

__global__ __launch_bounds__(256) void pack_x(const float* __restrict__ x,
                                              short* __restrict__ xB) {
  size_t i = (size_t)blockIdx.x * 256 + threadIdx.x;   // 4,194,304 total
  int l = (int)(i & 63);
  size_t r = i >> 6;
  int kb = (int)(r & 7); r >>= 3;
  int nb = (int)(r & 1023);
  int b = (int)(r >> 10);
  int t = (nb << 4) + (l & 15);
  int c0 = (kb << 5) + ((l >> 4) << 3);
  const float* xs = x + (size_t)(b * 256 + c0) * 16384 + t;
  s16x8 v;
#pragma unroll
  for (int j = 0; j < 8; ++j) v[j] = f2bf(xs[(size_t)j * 16384]);
  *(s16x8*)(xB + (i << 3)) = v;
}

__global__ __launch_bounds__(256) void pack_fg(const float* __restrict__ Wf,
                                               const float* __restrict__ Wg,
                                               short* __restrict__ A) {
  int i = blockIdx.x * 256 + threadIdx.x;
  if (i >= 30 * 256 * 256) return;
  int l = i >> 16, rem = i & 65535;
  int m = rem >> 8, k = rem & 255;
  int ic = k & 127, tap = k >> 7;
  float v = (m < 128)
      ? Wf[((size_t)(l * 128 + m) * 128 + ic) * 2 + tap]
      : Wg[((size_t)(l * 128 + (m - 128)) * 128 + ic) * 2 + tap];
  A[(size_t)l * 65536 + frag_idx(m, k, 256)] = f2bf(v);
}

__global__ __launch_bounds__(256) void pack_mats(const float* __restrict__ W,
                                                 short* __restrict__ A,
                                                 int M, int K, int total) {
  int i = blockIdx.x * 256 + threadIdx.x;
  if (i >= total) return;
  int mk = M * K;
  int l = i / mk, rem = i - l * mk;
  int m = rem / K, k = rem - m * K;
  A[(size_t)l * mk + frag_idx(m, k, K)] = f2bf(W[i]);
}

__global__ void sum_bs_k(const float* __restrict__ bs, float* __restrict__ sbs) {
  int c = threadIdx.x;
  float s = 0.f;
  for (int l = 0; l < 30; ++l) s += bs[l * 256 + c];
  sbs[c] = s;
}

__global__ __launch_bounds__(256) void sentinel_fill(float* __restrict__ out, int n) {
  int i = blockIdx.x * 256 + threadIdx.x;
  if (i < n) out[i] = -54321.0f;
}

// ---------------- initial 1x1 conv: h0 = W_init x + b_init ------------------

__global__ __launch_bounds__(256) void init_kernel(const short* __restrict__ xB,
                                                   const short* __restrict__ Ai,
                                                   const float* __restrict__ b_init,
                                                   float* __restrict__ h0) {
  __shared__ __align__(16) float rl[64 * 128];
  const int tid = threadIdx.x, lane = tid & 63, w = tid >> 6;
  const int b = blockIdx.x >> 8, t0 = (blockIdx.x & 255) << 6;
  const short* __restrict__ xb = xB + (size_t)((b << 10) + (t0 >> 4)) * 4096;
  f32x4 acc[2][4] = {};
#pragma unroll
  for (int kb = 0; kb < 8; ++kb) {
    s16x8 bx[4];
#pragma unroll
    for (int nb = 0; nb < 4; ++nb)
      bx[nb] = *(const s16x8*)(xb + (((nb * 8 + kb) * 64 + lane) << 3));
#pragma unroll
    for (int mi = 0; mi < 2; ++mi) {
      s16x8 a = *(const s16x8*)(Ai + ((((2 * w + mi) * 8 + kb) * 64 + lane) << 3));
#pragma unroll
      for (int nb = 0; nb < 4; ++nb) acc[mi][nb] = mfma16(a, bx[nb], acc[mi][nb]);
    }
  }
  const int qrow = (lane >> 4) << 2;
#pragma unroll
  for (int mi = 0; mi < 2; ++mi) {
    const int c0 = 32 * w + 16 * mi + qrow;
#pragma unroll
    for (int nb = 0; nb < 4; ++nb) {
      const int tl = nb * 16 + (lane & 15);
      *(f32x4*)((char*)rl + swzf128(tl, c0)) = acc[mi][nb];
    }
  }
  __syncthreads();
  float* __restrict__ ho = h0 + ((size_t)b * 16384 + t0) * 128;
#pragma unroll
  for (int it = 0; it < 8; ++it) {
    int lin = it * 256 + tid;
    int row = lin >> 5, sl = lin & 31;
    f32x4 rv = *(const f32x4*)((char*)rl + swzf128(row, sl * 4));
    f32x4 ov;
#pragma unroll
    for (int j = 0; j < 4; ++j) ov[j] = rv[j] + b_init[sl * 4 + j];
    *(f32x4*)(ho + (size_t)row * 128 + sl * 4) = ov;
  }
}

// ---------------- residual layer: 512 threads / 8 waves ---------------------
// f = tanh(Wf0 h[t-d] + Wf1 h[t] + bf), g = sigm(...), z = f*g
// h_out = h_in + Wr z + br ; skip (+)= Ws z   (bf16 RMW, layer0 plain write)

__global__ __launch_bounds__(512, 4) void layer_kernel(
    const float* __restrict__ h_in, float* __restrict__ h_out,
    const short* __restrict__ Afg, const short* __restrict__ Ar,
    const short* __restrict__ As, short* __restrict__ skip,
    const float* __restrict__ bfv, const float* __restrict__ bgv,
    const float* __restrict__ brv, int d, int first) {
  __shared__ __align__(16) short hl[128 * 128];   // 32KB, multi-purpose
  const int tid = threadIdx.x, lane = tid & 63, w = tid >> 6;   // w in 0..7
  const int b = blockIdx.x >> 8, t0 = (blockIdx.x & 255) << 6;
  const int qrow = (lane >> 4) << 2;
  const float* __restrict__ hb = h_in + (size_t)b * 16384 * 128;
  short* __restrict__ sk = skip + ((size_t)b * 16384 + t0) * 256;

  // P0: prefetch skip tile into registers (independent of all compute)
  s16x8 pv[4];
  if (!first) {
#pragma unroll
    for (int it = 0; it < 4; ++it) {
      int lin = it * 512 + tid;
      int row = lin >> 5, sl = lin & 31;
      pv[it] = *(const s16x8*)(sk + (size_t)row * 256 + sl * 8);
    }
  }

  // P1: stage h tiles -> LDS bf16; keep cur rows fp32 in regs for epilogue
  f32x4 hc[2][2];
#pragma unroll
  for (int it = 0; it < 4; ++it) {
    int lin = it * 512 + tid;
    int r = lin >> 4, s = lin & 15;
    int tg = (r < 64) ? (t0 - d + r) : (t0 + r - 64);
    s16x8 v;
    if (tg < 0) {
      v = (s16x8)0;
    } else {
      const float* src = hb + (size_t)tg * 128 + s * 8;
      f32x4 a0 = *(const f32x4*)src;
      f32x4 a1 = *(const f32x4*)(src + 4);
      if (it >= 2) { hc[it - 2][0] = a0; hc[it - 2][1] = a1; }
      union { s16x8 v; uint32_t u[4]; } cv;
      cv.u[0] = cvtpk(a0[0], a0[1]); cv.u[1] = cvtpk(a0[2], a0[3]);
      cv.u[2] = cvtpk(a1[0], a1[1]); cv.u[3] = cvtpk(a1[2], a1[3]);
      v = cv.v;
    }
    *(s16x8*)((char*)hl + swz128(r, s * 8)) = v;
  }
  __syncthreads();

  // P2: FG GEMM, M=256 stacked [f;g]; wave w: f-block mb=w, g-block mb=8+w
  f32x4 acc[2][4] = {};
#pragma unroll
  for (int kb = 0; kb < 8; ++kb) {
    const int rbase = (kb >= 4) ? 64 : 0;
    const int icb = (kb & 3) * 32 + ((lane >> 4) << 3);
    s16x8 bfr[4];
#pragma unroll
    for (int nb = 0; nb < 4; ++nb)
      bfr[nb] = *(const s16x8*)((const char*)hl + swz128(rbase + nb * 16 + (lane & 15), icb));
    s16x8 af = *(const s16x8*)(Afg + (((w * 8 + kb) * 64 + lane) << 3));
    s16x8 ag = *(const s16x8*)(Afg + ((((8 + w) * 8 + kb) * 64 + lane) << 3));
#pragma unroll
    for (int nb = 0; nb < 4; ++nb) {
      acc[0][nb] = mfma16(af, bfr[nb], acc[0][nb]);
      acc[1][nb] = mfma16(ag, bfr[nb], acc[1][nb]);
    }
  }
  __syncthreads();   // all hl reads done; overlay z

  // P3: gated activation; z -> LDS (rows 0..63 of hl)
  const int c0z = 16 * w + qrow;
#pragma unroll
  for (int nb = 0; nb < 4; ++nb) {
    const int tl = nb * 16 + (lane & 15);
    float zv4[4];
#pragma unroll
    for (int r = 0; r < 4; ++r) {
      float fv = acc[0][nb][r] + bfv[c0z + r];
      float gv = acc[1][nb][r] + bgv[c0z + r];
      float th = 1.f - 2.f * fast_rcp(__expf(2.f * fv) + 1.f);
      float sg = fast_rcp(1.f + __expf(-gv));
      zv4[r] = th * sg;
    }
    union { s16x4 v; uint32_t u[2]; } cv;
    cv.u[0] = cvtpk(zv4[0], zv4[1]); cv.u[1] = cvtpk(zv4[2], zv4[3]);
    *(s16x4*)((char*)hl + swz128(tl, c0z)) = cv.v;
  }
  __syncthreads();

  // P4: merged R (mb=w) + S (mb=w, 8+w) GEMM over shared z B-fragments, K=128
  f32x4 racc[4] = {};
  f32x4 sacc[2][4] = {};
#pragma unroll
  for (int kb = 0; kb < 4; ++kb) {
    const int icb = kb * 32 + ((lane >> 4) << 3);
    s16x8 bz[4];
#pragma unroll
    for (int nb = 0; nb < 4; ++nb)
      bz[nb] = *(const s16x8*)((const char*)hl + swz128(nb * 16 + (lane & 15), icb));
    s16x8 ar  = *(const s16x8*)(Ar + (((w * 4 + kb) * 64 + lane) << 3));
    s16x8 as0 = *(const s16x8*)(As + (((w * 4 + kb) * 64 + lane) << 3));
    s16x8 as1 = *(const s16x8*)(As + ((((8 + w) * 4 + kb) * 64 + lane) << 3));
#pragma unroll
    for (int nb = 0; nb < 4; ++nb) {
      racc[nb]    = mfma16(ar,  bz[nb], racc[nb]);
      sacc[0][nb] = mfma16(as0, bz[nb], sacc[0][nb]);
      sacc[1][nb] = mfma16(as1, bz[nb], sacc[1][nb]);
    }
  }
  __syncthreads();   // z reads done; reuse hl as f32 r-tile

  // P5: racc -> LDS f32 [64][128]
#pragma unroll
  for (int nb = 0; nb < 4; ++nb) {
    const int tl = nb * 16 + (lane & 15);
    *(f32x4*)((char*)hl + swzf128(tl, c0z)) = racc[nb];
  }
  __syncthreads();

  // P6: coalesced h_out = h_in(regs) + r + br
  {
    float* __restrict__ ho = h_out + ((size_t)b * 16384 + t0) * 128;
    const int s = tid & 15;
#pragma unroll
    for (int it = 0; it < 2; ++it) {
      const int row = (tid >> 4) + it * 32;
      f32x4 rv0 = *(const f32x4*)((const char*)hl + swzf128(row, s * 8));
      f32x4 rv1 = *(const f32x4*)((const char*)hl + swzf128(row, s * 8 + 4));
      f32x4 ov0, ov1;
#pragma unroll
      for (int j = 0; j < 4; ++j) {
        ov0[j] = hc[it][0][j] + rv0[j] + brv[s * 8 + j];
        ov1[j] = hc[it][1][j] + rv1[j] + brv[s * 8 + 4 + j];
      }
      *(f32x4*)(ho + (size_t)row * 128 + s * 8) = ov0;
      *(f32x4*)(ho + (size_t)row * 128 + s * 8 + 4) = ov1;
    }
  }
  __syncthreads();   // r-tile reads done; reuse hl as bf16 skip tile

  // P7: sacc -> LDS bf16 [64][256]
#pragma unroll
  for (int mi = 0; mi < 2; ++mi) {
    const int c0 = mi * 128 + 16 * w + qrow;
#pragma unroll
    for (int nb = 0; nb < 4; ++nb) {
      const int tl = nb * 16 + (lane & 15);
      union { s16x4 v; uint32_t u[2]; } cv;
      cv.u[0] = cvtpk(sacc[mi][nb][0], sacc[mi][nb][1]);
      cv.u[1] = cvtpk(sacc[mi][nb][2], sacc[mi][nb][3]);
      *(s16x4*)((char*)hl + swz256(tl, c0)) = cv.v;
    }
  }
  __syncthreads();

  // P8: coalesced skip RMW (bf16) using prefetched pv
#pragma unroll
  for (int it = 0; it < 4; ++it) {
    int lin = it * 512 + tid;
    int row = lin >> 5, sl = lin & 31;
    s16x8 zv = *(const s16x8*)((char*)hl + swz256(row, sl * 8));
    s16x8 ov;
    if (first) {
      ov = zv;
    } else {
      union { s16x8 v; uint32_t u[4]; } cv;
#pragma unroll
      for (int jj = 0; jj < 4; ++jj)
        cv.u[jj] = cvtpk(bf2f(pv[it][2 * jj]) + bf2f(zv[2 * jj]),
                         bf2f(pv[it][2 * jj + 1]) + bf2f(zv[2 * jj + 1]));
      ov = cv.v;
    }
    *(s16x8*)(sk + (size_t)row * 256 + sl * 8) = ov;
  }
}

// ---------------- final: relu(skip+sbs) -> W1 -> relu -> W2 -> out ----------

__global__ __launch_bounds__(256) void final_kernel(
    const short* __restrict__ skip, const short* __restrict__ A1,
    const short* __restrict__ A2, const float* __restrict__ sbs,
    const float* __restrict__ b1, const float* __restrict__ b2,
    float* __restrict__ out) {
  __shared__ __align__(16) short sb[64 * 256];
  const int tid = threadIdx.x, lane = tid & 63, w = tid >> 6;
  const int b = blockIdx.x >> 8, t0 = (blockIdx.x & 255) << 6;
  const int qrow = (lane >> 4) << 2;

  // stage relu(skip + sbs) -> sb (bf16, swizzled)
  const short* __restrict__ sk = skip + ((size_t)b * 16384 + t0) * 256;
#pragma unroll
  for (int it = 0; it < 8; ++it) {
    int lin = it * 256 + tid;
    int r = lin >> 5, cs = (lin & 31) << 3;
    s16x8 sv = *(const s16x8*)(sk + (size_t)r * 256 + cs);
    union { s16x8 v; uint32_t u[4]; } cv;
#pragma unroll
    for (int jj = 0; jj < 4; ++jj)
      cv.u[jj] = cvtpk(fmaxf(bf2f(sv[2 * jj]) + sbs[cs + 2 * jj], 0.f),
                       fmaxf(bf2f(sv[2 * jj + 1]) + sbs[cs + 2 * jj + 1], 0.f));
    *(s16x8*)((char*)sb + swz256(r, cs)) = cv.v;
  }
  __syncthreads();

  // W1 GEMM (M=256,K=256)
  f32x4 a2[4][4] = {};
#pragma unroll
  for (int kb = 0; kb < 8; ++kb) {
    const int icb = kb * 32 + ((lane >> 4) << 3);
    s16x8 bs_[4];
#pragma unroll
    for (int nb = 0; nb < 4; ++nb)
      bs_[nb] = *(const s16x8*)((const char*)sb + swz256(nb * 16 + (lane & 15), icb));
#pragma unroll
    for (int mi = 0; mi < 4; ++mi) {
      s16x8 a = *(const s16x8*)(A1 + ((((4 * w + mi) * 8 + kb) * 64 + lane) << 3));
#pragma unroll
      for (int nb = 0; nb < 4; ++nb) a2[mi][nb] = mfma16(a, bs_[nb], a2[mi][nb]);
    }
  }
  __syncthreads();
#pragma unroll
  for (int mi = 0; mi < 4; ++mi) {
    const int c0 = (4 * w + mi) * 16 + qrow;
#pragma unroll
    for (int nb = 0; nb < 4; ++nb) {
      const int tl = nb * 16 + (lane & 15);
      union { s16x4 v; uint32_t u[2]; } cv;
      cv.u[0] = cvtpk(fmaxf(a2[mi][nb][0] + b1[c0], 0.f),
                      fmaxf(a2[mi][nb][1] + b1[c0 + 1], 0.f));
      cv.u[1] = cvtpk(fmaxf(a2[mi][nb][2] + b1[c0 + 2], 0.f),
                      fmaxf(a2[mi][nb][3] + b1[c0 + 3], 0.f));
      *(s16x4*)((char*)sb + swz256(tl, c0)) = cv.v;
    }
  }
  __syncthreads();

  // W2 GEMM -> out [B][256][T]
  f32x4 a3[4][4] = {};
#pragma unroll
  for (int kb = 0; kb < 8; ++kb) {
    const int icb = kb * 32 + ((lane >> 4) << 3);
    s16x8 bs_[4];
#pragma unroll
    for (int nb = 0; nb < 4; ++nb)
      bs_[nb] = *(const s16x8*)((const char*)sb + swz256(nb * 16 + (lane & 15), icb));
#pragma unroll
    for (int mi = 0; mi < 4; ++mi) {
      s16x8 a = *(const s16x8*)(A2 + ((((4 * w + mi) * 8 + kb) * 64 + lane) << 3));
#pragma unroll
      for (int nb = 0; nb < 4; ++nb) a3[mi][nb] = mfma16(a, bs_[nb], a3[mi][nb]);
    }
  }
#pragma unroll
  for (int mi = 0; mi < 4; ++mi) {
    const int c0 = (4 * w + mi) * 16 + qrow;
#pragma unroll
    for (int nb = 0; nb < 4; ++nb) {
      const int tg = t0 + nb * 16 + (lane & 15);
#pragma unroll
      for (int r = 0; r < 4; ++r)
        out[(size_t)(b * 256 + c0 + r) * 16384 + tg] = a3[mi][nb][r] + b2[c0 + r];
    }
  }
}

// ---------------- host orchestration ---------------------------------------

extern "C" void kernel_launch(void* const* d_in, const int* in_sizes, int n_in,
                              void* d_out, int out_size, void* d_ws, size_t ws_size,
                              hipStream_t stream) {
  (void)in_sizes; (void)n_in;
  const float* x      = (const float*)d_in[0];
  const float* W_init = (const float*)d_in[1];
  const float* b_init = (const float*)d_in[2];
  const float* Wf     = (const float*)d_in[3];
  const float* bf     = (const float*)d_in[4];
  const float* Wg     = (const float*)d_in[5];
  const float* bg     = (const float*)d_in[6];
  const float* Wr     = (const float*)d_in[7];
  const float* br     = (const float*)d_in[8];
  const float* Wsk    = (const float*)d_in[9];
  const float* bs     = (const float*)d_in[10];
  const float* W1     = (const float*)d_in[11];
  const float* b1     = (const float*)d_in[12];
  const float* W2     = (const float*)d_in[13];
  const float* b2     = (const float*)d_in[14];

  // h ping-pong carved out of d_out (134MB; each h is 67MB; dead before final)
  float* h_a = (float*)d_out;
  float* h_b = h_a + (size_t)8 * 16384 * 128;

  char* ws = (char*)d_ws;
  size_t off = 0;
  short* skip = (short*)(ws + off); off += (size_t)8 * 16384 * 256 * 2;      // 67MB
  short* xB   = (short*)(ws + off); off += (size_t)8 * 1024 * 8 * 64 * 8 * 2;// 67MB
  short* Afg  = (short*)(ws + off); off += (size_t)30 * 65536 * 2;
  short* Ar   = (short*)(ws + off); off += (size_t)30 * 16384 * 2;
  short* As   = (short*)(ws + off); off += (size_t)30 * 32768 * 2;
  short* Ai   = (short*)(ws + off); off += (size_t)32768 * 2;
  short* A1   = (short*)(ws + off); off += (size_t)65536 * 2;
  short* A2   = (short*)(ws + off); off += (size_t)65536 * 2;
  float* sbs  = (float*)(ws + off); off += 256 * 4;

  if (ws_size < off) {
    sentinel_fill<<<(out_size + 255) / 256, 256, 0, stream>>>((float*)d_out, out_size);
    return;
  }

  pack_x<<<16384, 256, 0, stream>>>(x, xB);
  pack_fg<<<7680, 256, 0, stream>>>(Wf, Wg, Afg);
  pack_mats<<<1920, 256, 0, stream>>>(Wr, Ar, 128, 128, 30 * 128 * 128);
  pack_mats<<<3840, 256, 0, stream>>>(Wsk, As, 256, 128, 30 * 256 * 128);
  pack_mats<<<128, 256, 0, stream>>>(W_init, Ai, 128, 256, 128 * 256);
  pack_mats<<<256, 256, 0, stream>>>(W1, A1, 256, 256, 256 * 256);
  pack_mats<<<256, 256, 0, stream>>>(W2, A2, 256, 256, 256 * 256);
  sum_bs_k<<<1, 256, 0, stream>>>(bs, sbs);

  init_kernel<<<2048, 256, 0, stream>>>(xB, Ai, b_init, h_a);

  float* hin = h_a; float* hout = h_b;
  for (int l = 0; l < 30; ++l) {
    int d = 1 << (l % 10);
    layer_kernel<<<2048, 512, 0, stream>>>(hin, hout,
        Afg + (size_t)l * 65536, Ar + (size_t)l * 16384, As + (size_t)l * 32768,
        skip, bf + l * 128, bg + l * 128, br + l * 128, d, l == 0 ? 1 : 0);
    float* tmp = hin; hin = hout; hout = tmp;
  }

  final_kernel<<<2048, 256, 0, stream>>>(skip, A1, A2, sbs, b1, b2, (float*)d_out);
}